// Round 7
// baseline (217.692 us; speedup 1.0000x reference)
//
#include <hip/hip_runtime.h>
#include <math.h>

namespace {
constexpr int kB   = 32;
constexpr int kIDF = 128;
constexpr int kCDF = 256;
constexpr int kSL  = 24;
constexpr int kQL  = 128 * 128;
constexpr int kThreads = 256;
constexpr int kQPT = 4;                    // q per thread (float4 path)
constexpr int kQPB = kThreads * kQPT;      // 1024 q per block

typedef float f32x4 __attribute__((ext_vector_type(4)));

// sourceT[b,i,l] = sum_c W[i,c] * context[b,c,l]
__global__ __launch_bounds__(kThreads) void proj_kernel(
    const float* __restrict__ W, const float* __restrict__ ctx,
    float* __restrict__ sT_out) {
  const int b = blockIdx.x;
  __shared__ float ctxs[kCDF * kSL];
  const float* ctxb = ctx + (size_t)b * kCDF * kSL;
  for (int t = threadIdx.x; t < kCDF * kSL; t += kThreads) ctxs[t] = ctxb[t];
  __syncthreads();
  #pragma unroll
  for (int k = 0; k < (kIDF * kSL) / kThreads; ++k) {
    const int o = threadIdx.x + k * kThreads;
    const int i = o / kSL, l = o % kSL;
    const float* wrow = W + i * kCDF;
    float acc = 0.f;
    #pragma unroll 8
    for (int c = 0; c < kCDF; ++c) acc = fmaf(wrow[c], ctxs[c * kSL + l], acc);
    sT_out[(size_t)b * kIDF * kSL + o] = acc;
  }
}

// Main attention kernel. sT reads are wave-uniform -> s_load/SGPR broadcast
// (no LDS, no barrier). QK loop is software-pipelined (double-buffered
// 8-load bursts) so global-load service overlaps the FMA tail; FMAs are
// written as f32x4 vector arithmetic to allow v_pk_fma_f32 formation.
__global__ __launch_bounds__(kThreads) void attn_scalar(
    const float* __restrict__ input, const float* __restrict__ sT_in,
    const int* __restrict__ mask, float* __restrict__ out_wc,
    float* __restrict__ out_attn) {
  const int b  = blockIdx.y;
  const int q0 = blockIdx.x * kQPB + threadIdx.x * kQPT;
  const float* __restrict__ sTb = sT_in + (size_t)b * kIDF * kSL;

  // mask bit set == position masked with -inf (weight 0)
  unsigned mbits = 0;
  #pragma unroll
  for (int l = 0; l < kSL; ++l) mbits |= (mask[b * kSL + l] ? 1u : 0u) << l;

  f32x4 acc[kSL];
  #pragma unroll
  for (int l = 0; l < kSL; ++l) acc[l] = (f32x4)0.f;

  const float* inb = input + (size_t)b * kIDF * kQL + q0;

#define LOAD8(BUF, II)                                                        \
  {                                                                           \
    _Pragma("unroll") for (int u = 0; u < 8; ++u)                             \
        BUF[u] = *reinterpret_cast<const f32x4*>(inb + (size_t)((II) + u) * kQL); \
  }
#define FMA8(BUF, II)                                                         \
  {                                                                           \
    _Pragma("unroll") for (int u = 0; u < 8; ++u) {                           \
      const float* wrow = sTb + ((II) + u) * kSL;                             \
      _Pragma("unroll") for (int l = 0; l < kSL; ++l)                         \
          acc[l] += BUF[u] * wrow[l];                                         \
    }                                                                         \
  }

  // attn[b,q,l] = sum_i input[b,i,q] * sT[i,l] — 16 bursts of 8 rows,
  // double-buffered so burst k+1 is in flight while burst k is consumed.
  {
    f32x4 bA[8], bB[8];
    LOAD8(bA, 0);
    #pragma unroll 1
    for (int k = 0; k < 14; k += 2) {
      LOAD8(bB, (k + 1) * 8);
      FMA8(bA, k * 8);
      LOAD8(bA, (k + 2) * 8);
      FMA8(bB, (k + 1) * 8);
    }
    LOAD8(bB, 15 * 8);
    FMA8(bA, 14 * 8);
    FMA8(bB, 15 * 8);
  }
#undef LOAD8
#undef FMA8

  // masked softmax over l (24), per q-component
  {
    float m[4] = {-INFINITY, -INFINITY, -INFINITY, -INFINITY};
    #pragma unroll
    for (int l = 0; l < kSL; ++l)
      if (!((mbits >> l) & 1u)) {
        #pragma unroll
        for (int c = 0; c < 4; ++c) m[c] = fmaxf(m[c], acc[l][c]);
      }
    float s[4] = {0.f, 0.f, 0.f, 0.f};
    #pragma unroll
    for (int l = 0; l < kSL; ++l) {
      const bool km = (mbits >> l) & 1u;
      #pragma unroll
      for (int c = 0; c < 4; ++c) {
        const float p = km ? 0.f : __expf(acc[l][c] - m[c]);
        acc[l][c] = p;
        s[c] += p;
      }
    }
    f32x4 r;
    #pragma unroll
    for (int c = 0; c < 4; ++c) r[c] = 1.f / s[c];
    #pragma unroll
    for (int l = 0; l < kSL; ++l) acc[l] *= r;
  }

  // attn_out[b,l,q] first — fills the store queue while PV computes.
  float* oa = out_attn + (size_t)b * kSL * kQL + q0;
  #pragma unroll
  for (int l = 0; l < kSL; ++l)
    __builtin_nontemporal_store(acc[l], reinterpret_cast<f32x4*>(oa + (size_t)l * kQL));

  // weightedContext[b,i,q] = sum_l sT[i,l] * attn[b,q,l]
  float* ow = out_wc + (size_t)b * kIDF * kQL + q0;
  #pragma unroll 1
  for (int ii = 0; ii < kIDF; ii += 8) {
    f32x4 res[8];
    #pragma unroll
    for (int u = 0; u < 8; ++u) res[u] = (f32x4)0.f;
    #pragma unroll
    for (int u = 0; u < 8; ++u) {
      const float* wrow = sTb + (ii + u) * kSL;
      #pragma unroll
      for (int l = 0; l < kSL; ++l) res[u] += acc[l] * wrow[l];
    }
    #pragma unroll
    for (int u = 0; u < 8; ++u)
      __builtin_nontemporal_store(res[u],
          reinterpret_cast<f32x4*>(ow + (size_t)(ii + u) * kQL));
  }
}

// Fallback (no workspace): compute sourceT per block in LDS.
__global__ __launch_bounds__(kThreads) void attn_fused(
    const float* __restrict__ input, const float* __restrict__ W,
    const float* __restrict__ ctx, const int* __restrict__ mask,
    float* __restrict__ out_wc, float* __restrict__ out_attn) {
  const int b  = blockIdx.y;
  const int q0 = blockIdx.x * kQPB + threadIdx.x * kQPT;
  constexpr int kSTN = kIDF * kSL;
  __shared__ float smem[kSTN + kCDF * kSL];
  float* sT = smem;
  {
    float* ctxs = smem + kSTN;
    const float* ctxb = ctx + (size_t)b * kCDF * kSL;
    for (int t = threadIdx.x; t < kCDF * kSL; t += kThreads) ctxs[t] = ctxb[t];
    __syncthreads();
    for (int k = 0; k < kSTN / kThreads; ++k) {
      const int o = threadIdx.x + k * kThreads;
      const int i = o / kSL, l = o % kSL;
      const float* wrow = W + i * kCDF;
      float a = 0.f;
      for (int c = 0; c < kCDF; ++c) a = fmaf(wrow[c], ctxs[c * kSL + l], a);
      sT[o] = a;
    }
  }
  __syncthreads();

  unsigned mbits = 0;
  #pragma unroll
  for (int l = 0; l < kSL; ++l) mbits |= (mask[b * kSL + l] ? 1u : 0u) << l;

  f32x4 acc[kSL];
  #pragma unroll
  for (int l = 0; l < kSL; ++l) acc[l] = (f32x4)0.f;

  const float* inb = input + (size_t)b * kIDF * kQL + q0;
  #pragma unroll 1
  for (int ii = 0; ii < kIDF; ii += 8) {
    f32x4 t[8];
    #pragma unroll
    for (int u = 0; u < 8; ++u)
      t[u] = *reinterpret_cast<const f32x4*>(inb + (size_t)(ii + u) * kQL);
    #pragma unroll
    for (int u = 0; u < 8; ++u) {
      const float* wrow = &sT[(ii + u) * kSL];
      #pragma unroll
      for (int l = 0; l < kSL; ++l) acc[l] += t[u] * wrow[l];
    }
  }

  {
    float m[4] = {-INFINITY, -INFINITY, -INFINITY, -INFINITY};
    #pragma unroll
    for (int l = 0; l < kSL; ++l)
      if (!((mbits >> l) & 1u)) {
        #pragma unroll
        for (int c = 0; c < 4; ++c) m[c] = fmaxf(m[c], acc[l][c]);
      }
    float s[4] = {0.f, 0.f, 0.f, 0.f};
    #pragma unroll
    for (int l = 0; l < kSL; ++l) {
      const bool km = (mbits >> l) & 1u;
      #pragma unroll
      for (int c = 0; c < 4; ++c) {
        const float p = km ? 0.f : __expf(acc[l][c] - m[c]);
        acc[l][c] = p;
        s[c] += p;
      }
    }
    f32x4 r;
    #pragma unroll
    for (int c = 0; c < 4; ++c) r[c] = 1.f / s[c];
    #pragma unroll
    for (int l = 0; l < kSL; ++l) acc[l] *= r;
  }

  float* oa = out_attn + (size_t)b * kSL * kQL + q0;
  #pragma unroll
  for (int l = 0; l < kSL; ++l)
    __builtin_nontemporal_store(acc[l], reinterpret_cast<f32x4*>(oa + (size_t)l * kQL));

  float* ow = out_wc + (size_t)b * kIDF * kQL + q0;
  #pragma unroll 1
  for (int ii = 0; ii < kIDF; ii += 8) {
    f32x4 res[8];
    #pragma unroll
    for (int u = 0; u < 8; ++u) res[u] = (f32x4)0.f;
    #pragma unroll
    for (int u = 0; u < 8; ++u) {
      const float* wrow = &sT[(ii + u) * kSL];
      #pragma unroll
      for (int l = 0; l < kSL; ++l) res[u] += acc[l] * wrow[l];
    }
    #pragma unroll
    for (int u = 0; u < 8; ++u)
      __builtin_nontemporal_store(res[u],
          reinterpret_cast<f32x4*>(ow + (size_t)(ii + u) * kQL));
  }
}
}  // namespace

extern "C" void kernel_launch(void* const* d_in, const int* in_sizes, int n_in,
                              void* d_out, int out_size, void* d_ws, size_t ws_size,
                              hipStream_t stream) {
  const float* input = (const float*)d_in[0];
  const float* ctx   = (const float*)d_in[1];
  const float* W     = (const float*)d_in[2];
  const int*   mask  = (const int*)d_in[3];
  float* out_wc   = (float*)d_out;
  float* out_attn = (float*)d_out + (size_t)kB * kIDF * kQL;

  const size_t st_bytes = (size_t)kB * kIDF * kSL * sizeof(float);
  dim3 grid(kQL / kQPB, kB);
  if (ws_size >= st_bytes) {
    float* sT = (float*)d_ws;
    proj_kernel<<<kB, kThreads, 0, stream>>>(W, ctx, sT);
    attn_scalar<<<grid, kThreads, 0, stream>>>(input, sT, mask, out_wc, out_attn);
  } else {
    attn_fused<<<grid, kThreads, 0, stream>>>(input, W, ctx, mask, out_wc, out_attn);
  }
}

// Round 9
// 174.871 us; speedup vs baseline: 1.2449x; 1.2449x over previous
//
#include <hip/hip_runtime.h>
#include <math.h>

namespace {
constexpr int kB   = 32;
constexpr int kIDF = 128;
constexpr int kCDF = 256;
constexpr int kSL  = 24;
constexpr int kQL  = 128 * 128;
constexpr int kThreads = 256;
constexpr int kQPT = 2;                    // q per thread (float2 path)
constexpr int kQPB = kThreads * kQPT;      // 512 q per block -> 1024 blocks

typedef float f32x2 __attribute__((ext_vector_type(2)));

// sourceT[b,i,l] = sum_c W[i,c] * context[b,c,l]
__global__ __launch_bounds__(kThreads) void proj_kernel(
    const float* __restrict__ W, const float* __restrict__ ctx,
    float* __restrict__ sT_out) {
  const int b = blockIdx.x;
  __shared__ float ctxs[kCDF * kSL];
  const float* ctxb = ctx + (size_t)b * kCDF * kSL;
  for (int t = threadIdx.x; t < kCDF * kSL; t += kThreads) ctxs[t] = ctxb[t];
  __syncthreads();
  #pragma unroll
  for (int k = 0; k < (kIDF * kSL) / kThreads; ++k) {
    const int o = threadIdx.x + k * kThreads;
    const int i = o / kSL, l = o % kSL;
    const float* wrow = W + i * kCDF;
    float acc = 0.f;
    #pragma unroll 8
    for (int c = 0; c < kCDF; ++c) acc = fmaf(wrow[c], ctxs[c * kSL + l], acc);
    sT_out[(size_t)b * kIDF * kSL + o] = acc;
  }
}

// Main attention kernel, QPT=2 for 16 waves/CU (4 waves/SIMD) so VALU work
// of some waves overlaps the vmcnt waits of others. sT reads are
// wave-uniform -> s_load/SGPR broadcast (no LDS, no barrier). Per-iteration
// 8-row load burst, compiler-scheduled (hand cross-iteration pipelining
// regressed 60% in round 7 — do not reintroduce).
__global__ __launch_bounds__(kThreads, 4) void attn_scalar(
    const float* __restrict__ input, const float* __restrict__ sT_in,
    const int* __restrict__ mask, float* __restrict__ out_wc,
    float* __restrict__ out_attn) {
  const int b  = blockIdx.y;
  const int q0 = blockIdx.x * kQPB + threadIdx.x * kQPT;
  const float* __restrict__ sTb = sT_in + (size_t)b * kIDF * kSL;

  // mask bit set == position masked with -inf (weight 0)
  unsigned mbits = 0;
  #pragma unroll
  for (int l = 0; l < kSL; ++l) mbits |= (mask[b * kSL + l] ? 1u : 0u) << l;

  f32x2 acc[kSL];
  #pragma unroll
  for (int l = 0; l < kSL; ++l) acc[l] = (f32x2)0.f;

  // attn[b,q,l] = sum_i input[b,i,q] * sT[i,l]
  const float* inb = input + (size_t)b * kIDF * kQL + q0;
  #pragma unroll 1
  for (int ii = 0; ii < kIDF; ii += 8) {
    f32x2 t[8];
    #pragma unroll
    for (int u = 0; u < 8; ++u)
      t[u] = *reinterpret_cast<const f32x2*>(inb + (size_t)(ii + u) * kQL);
    #pragma unroll
    for (int u = 0; u < 8; ++u) {
      const float* wrow = sTb + (ii + u) * kSL;  // uniform -> s_load
      #pragma unroll
      for (int l = 0; l < kSL; ++l) acc[l] += t[u] * wrow[l];
    }
  }

  // masked softmax over l (24), per q-component
  {
    float m[2] = {-INFINITY, -INFINITY};
    #pragma unroll
    for (int l = 0; l < kSL; ++l)
      if (!((mbits >> l) & 1u)) {
        #pragma unroll
        for (int c = 0; c < 2; ++c) m[c] = fmaxf(m[c], acc[l][c]);
      }
    float s[2] = {0.f, 0.f};
    #pragma unroll
    for (int l = 0; l < kSL; ++l) {
      const bool km = (mbits >> l) & 1u;
      #pragma unroll
      for (int c = 0; c < 2; ++c) {
        const float p = km ? 0.f : __expf(acc[l][c] - m[c]);
        acc[l][c] = p;
        s[c] += p;
      }
    }
    f32x2 r;
    #pragma unroll
    for (int c = 0; c < 2; ++c) r[c] = 1.f / s[c];
    #pragma unroll
    for (int l = 0; l < kSL; ++l) acc[l] *= r;
  }

  // attn_out[b,l,q] — streamed once, nontemporal
  float* oa = out_attn + (size_t)b * kSL * kQL + q0;
  #pragma unroll
  for (int l = 0; l < kSL; ++l)
    __builtin_nontemporal_store(acc[l], reinterpret_cast<f32x2*>(oa + (size_t)l * kQL));

  // weightedContext[b,i,q] = sum_l sT[i,l] * attn[b,q,l]
  float* ow = out_wc + (size_t)b * kIDF * kQL + q0;
  #pragma unroll 1
  for (int ii = 0; ii < kIDF; ii += 8) {
    f32x2 res[8];
    #pragma unroll
    for (int u = 0; u < 8; ++u) res[u] = (f32x2)0.f;
    #pragma unroll
    for (int u = 0; u < 8; ++u) {
      const float* wrow = sTb + (ii + u) * kSL;  // uniform -> s_load (cached)
      #pragma unroll
      for (int l = 0; l < kSL; ++l) res[u] += acc[l] * wrow[l];
    }
    #pragma unroll
    for (int u = 0; u < 8; ++u)
      __builtin_nontemporal_store(res[u],
          reinterpret_cast<f32x2*>(ow + (size_t)(ii + u) * kQL));
  }
}

// Fallback (no workspace): compute sourceT per block in LDS.
__global__ __launch_bounds__(kThreads) void attn_fused(
    const float* __restrict__ input, const float* __restrict__ W,
    const float* __restrict__ ctx, const int* __restrict__ mask,
    float* __restrict__ out_wc, float* __restrict__ out_attn) {
  const int b  = blockIdx.y;
  const int q0 = blockIdx.x * kQPB + threadIdx.x * kQPT;
  constexpr int kSTN = kIDF * kSL;
  __shared__ float smem[kSTN + kCDF * kSL];
  float* sT = smem;
  {
    float* ctxs = smem + kSTN;
    const float* ctxb = ctx + (size_t)b * kCDF * kSL;
    for (int t = threadIdx.x; t < kCDF * kSL; t += kThreads) ctxs[t] = ctxb[t];
    __syncthreads();
    for (int k = 0; k < kSTN / kThreads; ++k) {
      const int o = threadIdx.x + k * kThreads;
      const int i = o / kSL, l = o % kSL;
      const float* wrow = W + i * kCDF;
      float a = 0.f;
      for (int c = 0; c < kCDF; ++c) a = fmaf(wrow[c], ctxs[c * kSL + l], a);
      sT[o] = a;
    }
  }
  __syncthreads();

  unsigned mbits = 0;
  #pragma unroll
  for (int l = 0; l < kSL; ++l) mbits |= (mask[b * kSL + l] ? 1u : 0u) << l;

  f32x2 acc[kSL];
  #pragma unroll
  for (int l = 0; l < kSL; ++l) acc[l] = (f32x2)0.f;

  const float* inb = input + (size_t)b * kIDF * kQL + q0;
  #pragma unroll 1
  for (int ii = 0; ii < kIDF; ii += 8) {
    f32x2 t[8];
    #pragma unroll
    for (int u = 0; u < 8; ++u)
      t[u] = *reinterpret_cast<const f32x2*>(inb + (size_t)(ii + u) * kQL);
    #pragma unroll
    for (int u = 0; u < 8; ++u) {
      const float* wrow = &sT[(ii + u) * kSL];
      #pragma unroll
      for (int l = 0; l < kSL; ++l) acc[l] += t[u] * wrow[l];
    }
  }

  {
    float m[2] = {-INFINITY, -INFINITY};
    #pragma unroll
    for (int l = 0; l < kSL; ++l)
      if (!((mbits >> l) & 1u)) {
        #pragma unroll
        for (int c = 0; c < 2; ++c) m[c] = fmaxf(m[c], acc[l][c]);
      }
    float s[2] = {0.f, 0.f};
    #pragma unroll
    for (int l = 0; l < kSL; ++l) {
      const bool km = (mbits >> l) & 1u;
      #pragma unroll
      for (int c = 0; c < 2; ++c) {
        const float p = km ? 0.f : __expf(acc[l][c] - m[c]);
        acc[l][c] = p;
        s[c] += p;
      }
    }
    f32x2 r;
    #pragma unroll
    for (int c = 0; c < 2; ++c) r[c] = 1.f / s[c];
    #pragma unroll
    for (int l = 0; l < kSL; ++l) acc[l] *= r;
  }

  float* oa = out_attn + (size_t)b * kSL * kQL + q0;
  #pragma unroll
  for (int l = 0; l < kSL; ++l)
    __builtin_nontemporal_store(acc[l], reinterpret_cast<f32x2*>(oa + (size_t)l * kQL));

  float* ow = out_wc + (size_t)b * kIDF * kQL + q0;
  #pragma unroll 1
  for (int ii = 0; ii < kIDF; ii += 8) {
    f32x2 res[8];
    #pragma unroll
    for (int u = 0; u < 8; ++u) res[u] = (f32x2)0.f;
    #pragma unroll
    for (int u = 0; u < 8; ++u) {
      const float* wrow = &sT[(ii + u) * kSL];
      #pragma unroll
      for (int l = 0; l < kSL; ++l) res[u] += acc[l] * wrow[l];
    }
    #pragma unroll
    for (int u = 0; u < 8; ++u)
      __builtin_nontemporal_store(res[u],
          reinterpret_cast<f32x2*>(ow + (size_t)(ii + u) * kQL));
  }
}
}  // namespace

extern "C" void kernel_launch(void* const* d_in, const int* in_sizes, int n_in,
                              void* d_out, int out_size, void* d_ws, size_t ws_size,
                              hipStream_t stream) {
  const float* input = (const float*)d_in[0];
  const float* ctx   = (const float*)d_in[1];
  const float* W     = (const float*)d_in[2];
  const int*   mask  = (const int*)d_in[3];
  float* out_wc   = (float*)d_out;
  float* out_attn = (float*)d_out + (size_t)kB * kIDF * kQL;

  const size_t st_bytes = (size_t)kB * kIDF * kSL * sizeof(float);
  dim3 grid(kQL / kQPB, kB);
  if (ws_size >= st_bytes) {
    float* sT = (float*)d_ws;
    proj_kernel<<<kB, kThreads, 0, stream>>>(W, ctx, sT);
    attn_scalar<<<grid, kThreads, 0, stream>>>(input, sT, mask, out_wc, out_attn);
  } else {
    attn_fused<<<grid, kThreads, 0, stream>>>(input, W, ctx, mask, out_wc, out_attn);
  }
}

// Round 11
// 169.494 us; speedup vs baseline: 1.2844x; 1.0317x over previous
//
#include <hip/hip_runtime.h>
#include <math.h>

namespace {
constexpr int kB   = 32;
constexpr int kIDF = 128;
constexpr int kCDF = 256;
constexpr int kSL  = 24;
constexpr int kQL  = 128 * 128;
constexpr int kThreads = 256;
constexpr int kQPT = 4;                    // q per thread (float4 path)
constexpr int kQPB = kThreads * kQPT;      // 1024 q per block

typedef float f32x4 __attribute__((ext_vector_type(4)));

// sourceT[b,i,l] = sum_c W[i,c] * context[b,c,l]
__global__ __launch_bounds__(kThreads) void proj_kernel(
    const float* __restrict__ W, const float* __restrict__ ctx,
    float* __restrict__ sT_out) {
  const int b = blockIdx.x;
  __shared__ float ctxs[kCDF * kSL];
  const float* ctxb = ctx + (size_t)b * kCDF * kSL;
  for (int t = threadIdx.x; t < kCDF * kSL; t += kThreads) ctxs[t] = ctxb[t];
  __syncthreads();
  #pragma unroll
  for (int k = 0; k < (kIDF * kSL) / kThreads; ++k) {
    const int o = threadIdx.x + k * kThreads;
    const int i = o / kSL, l = o % kSL;
    const float* wrow = W + i * kCDF;
    float acc = 0.f;
    #pragma unroll 8
    for (int c = 0; c < kCDF; ++c) acc = fmaf(wrow[c], ctxs[c * kSL + l], acc);
    sT_out[(size_t)b * kIDF * kSL + o] = acc;
  }
}

// Main attention kernel (QPT=4, scalar-sT via wave-uniform s_load, NT
// stores). NEW vs r5: raw s_barrier (no waitcnt semantics — __syncthreads
// would emit vmcnt(0) drains, the round-7 regression) phase-locks the 4
// waves of the block at every load/store burst, so their 1KB pieces of
// each 64KB-strided row coalesce into contiguous 4KB runs at the memory
// controller (DRAM row-buffer locality). No LDS -> barrier is purely a
// scheduling device, no correctness dependency.
__global__ __launch_bounds__(kThreads) void attn_scalar(
    const float* __restrict__ input, const float* __restrict__ sT_in,
    const int* __restrict__ mask, float* __restrict__ out_wc,
    float* __restrict__ out_attn) {
  const int b  = blockIdx.y;
  const int q0 = blockIdx.x * kQPB + threadIdx.x * kQPT;
  const float* __restrict__ sTb = sT_in + (size_t)b * kIDF * kSL;

  // mask bit set == position masked with -inf (weight 0)
  unsigned mbits = 0;
  #pragma unroll
  for (int l = 0; l < kSL; ++l) mbits |= (mask[b * kSL + l] ? 1u : 0u) << l;

  f32x4 acc[kSL];
  #pragma unroll
  for (int l = 0; l < kSL; ++l) acc[l] = (f32x4)0.f;

  // attn[b,q,l] = sum_i input[b,i,q] * sT[i,l]
  const float* inb = input + (size_t)b * kIDF * kQL + q0;
  #pragma unroll 1
  for (int ii = 0; ii < kIDF; ii += 8) {
    __builtin_amdgcn_s_barrier();  // align the 4 waves' load issue
    f32x4 t[8];
    #pragma unroll
    for (int u = 0; u < 8; ++u)
      t[u] = *reinterpret_cast<const f32x4*>(inb + (size_t)(ii + u) * kQL);
    #pragma unroll
    for (int u = 0; u < 8; ++u) {
      const float* wrow = sTb + (ii + u) * kSL;  // uniform -> s_load
      #pragma unroll
      for (int l = 0; l < kSL; ++l) acc[l] += t[u] * wrow[l];
    }
  }

  // masked softmax over l (24), per q-component
  {
    float m[4] = {-INFINITY, -INFINITY, -INFINITY, -INFINITY};
    #pragma unroll
    for (int l = 0; l < kSL; ++l)
      if (!((mbits >> l) & 1u)) {
        #pragma unroll
        for (int c = 0; c < 4; ++c) m[c] = fmaxf(m[c], acc[l][c]);
      }
    float s[4] = {0.f, 0.f, 0.f, 0.f};
    #pragma unroll
    for (int l = 0; l < kSL; ++l) {
      const bool km = (mbits >> l) & 1u;
      #pragma unroll
      for (int c = 0; c < 4; ++c) {
        const float p = km ? 0.f : __expf(acc[l][c] - m[c]);
        acc[l][c] = p;
        s[c] += p;
      }
    }
    f32x4 r;
    #pragma unroll
    for (int c = 0; c < 4; ++c) r[c] = 1.f / s[c];
    #pragma unroll
    for (int l = 0; l < kSL; ++l) acc[l] *= r;
  }

  // attn_out[b,l,q] — one aligned NT store burst
  __builtin_amdgcn_s_barrier();
  float* oa = out_attn + (size_t)b * kSL * kQL + q0;
  #pragma unroll
  for (int l = 0; l < kSL; ++l)
    __builtin_nontemporal_store(acc[l], reinterpret_cast<f32x4*>(oa + (size_t)l * kQL));

  // weightedContext[b,i,q] = sum_l sT[i,l] * attn[b,q,l]
  float* ow = out_wc + (size_t)b * kIDF * kQL + q0;
  #pragma unroll 1
  for (int ii = 0; ii < kIDF; ii += 8) {
    f32x4 res[8];
    #pragma unroll
    for (int u = 0; u < 8; ++u) res[u] = (f32x4)0.f;
    #pragma unroll
    for (int u = 0; u < 8; ++u) {
      const float* wrow = sTb + (ii + u) * kSL;  // uniform -> s_load (cached)
      #pragma unroll
      for (int l = 0; l < kSL; ++l) res[u] += acc[l] * wrow[l];
    }
    __builtin_amdgcn_s_barrier();  // align the 4 waves' store burst
    #pragma unroll
    for (int u = 0; u < 8; ++u)
      __builtin_nontemporal_store(res[u],
          reinterpret_cast<f32x4*>(ow + (size_t)(ii + u) * kQL));
  }
}

// Fallback (no workspace): compute sourceT per block in LDS.
__global__ __launch_bounds__(kThreads) void attn_fused(
    const float* __restrict__ input, const float* __restrict__ W,
    const float* __restrict__ ctx, const int* __restrict__ mask,
    float* __restrict__ out_wc, float* __restrict__ out_attn) {
  const int b  = blockIdx.y;
  const int q0 = blockIdx.x * kQPB + threadIdx.x * kQPT;
  constexpr int kSTN = kIDF * kSL;
  __shared__ float smem[kSTN + kCDF * kSL];
  float* sT = smem;
  {
    float* ctxs = smem + kSTN;
    const float* ctxb = ctx + (size_t)b * kCDF * kSL;
    for (int t = threadIdx.x; t < kCDF * kSL; t += kThreads) ctxs[t] = ctxb[t];
    __syncthreads();
    for (int k = 0; k < kSTN / kThreads; ++k) {
      const int o = threadIdx.x + k * kThreads;
      const int i = o / kSL, l = o % kSL;
      const float* wrow = W + i * kCDF;
      float a = 0.f;
      for (int c = 0; c < kCDF; ++c) a = fmaf(wrow[c], ctxs[c * kSL + l], a);
      sT[o] = a;
    }
  }
  __syncthreads();

  unsigned mbits = 0;
  #pragma unroll
  for (int l = 0; l < kSL; ++l) mbits |= (mask[b * kSL + l] ? 1u : 0u) << l;

  f32x4 acc[kSL];
  #pragma unroll
  for (int l = 0; l < kSL; ++l) acc[l] = (f32x4)0.f;

  const float* inb = input + (size_t)b * kIDF * kQL + q0;
  #pragma unroll 1
  for (int ii = 0; ii < kIDF; ii += 8) {
    f32x4 t[8];
    #pragma unroll
    for (int u = 0; u < 8; ++u)
      t[u] = *reinterpret_cast<const f32x4*>(inb + (size_t)(ii + u) * kQL);
    #pragma unroll
    for (int u = 0; u < 8; ++u) {
      const float* wrow = &sT[(ii + u) * kSL];
      #pragma unroll
      for (int l = 0; l < kSL; ++l) acc[l] += t[u] * wrow[l];
    }
  }

  {
    float m[4] = {-INFINITY, -INFINITY, -INFINITY, -INFINITY};
    #pragma unroll
    for (int l = 0; l < kSL; ++l)
      if (!((mbits >> l) & 1u)) {
        #pragma unroll
        for (int c = 0; c < 4; ++c) m[c] = fmaxf(m[c], acc[l][c]);
      }
    float s[4] = {0.f, 0.f, 0.f, 0.f};
    #pragma unroll
    for (int l = 0; l < kSL; ++l) {
      const bool km = (mbits >> l) & 1u;
      #pragma unroll
      for (int c = 0; c < 4; ++c) {
        const float p = km ? 0.f : __expf(acc[l][c] - m[c]);
        acc[l][c] = p;
        s[c] += p;
      }
    }
    f32x4 r;
    #pragma unroll
    for (int c = 0; c < 4; ++c) r[c] = 1.f / s[c];
    #pragma unroll
    for (int l = 0; l < kSL; ++l) acc[l] *= r;
  }

  float* oa = out_attn + (size_t)b * kSL * kQL + q0;
  #pragma unroll
  for (int l = 0; l < kSL; ++l)
    __builtin_nontemporal_store(acc[l], reinterpret_cast<f32x4*>(oa + (size_t)l * kQL));

  float* ow = out_wc + (size_t)b * kIDF * kQL + q0;
  #pragma unroll 1
  for (int ii = 0; ii < kIDF; ii += 8) {
    f32x4 res[8];
    #pragma unroll
    for (int u = 0; u < 8; ++u) res[u] = (f32x4)0.f;
    #pragma unroll
    for (int u = 0; u < 8; ++u) {
      const float* wrow = &sT[(ii + u) * kSL];
      #pragma unroll
      for (int l = 0; l < kSL; ++l) res[u] += acc[l] * wrow[l];
    }
    #pragma unroll
    for (int u = 0; u < 8; ++u)
      __builtin_nontemporal_store(res[u],
          reinterpret_cast<f32x4*>(ow + (size_t)(ii + u) * kQL));
  }
}
}  // namespace

extern "C" void kernel_launch(void* const* d_in, const int* in_sizes, int n_in,
                              void* d_out, int out_size, void* d_ws, size_t ws_size,
                              hipStream_t stream) {
  const float* input = (const float*)d_in[0];
  const float* ctx   = (const float*)d_in[1];
  const float* W     = (const float*)d_in[2];
  const int*   mask  = (const int*)d_in[3];
  float* out_wc   = (float*)d_out;
  float* out_attn = (float*)d_out + (size_t)kB * kIDF * kQL;

  const size_t st_bytes = (size_t)kB * kIDF * kSL * sizeof(float);
  dim3 grid(kQL / kQPB, kB);
  if (ws_size >= st_bytes) {
    float* sT = (float*)d_ws;
    proj_kernel<<<kB, kThreads, 0, stream>>>(W, ctx, sT);
    attn_scalar<<<grid, kThreads, 0, stream>>>(input, sT, mask, out_wc, out_attn);
  } else {
    attn_fused<<<grid, kThreads, 0, stream>>>(input, W, ctx, mask, out_wc, out_attn);
  }
}

// Round 12
// 165.643 us; speedup vs baseline: 1.3142x; 1.0233x over previous
//
#include <hip/hip_runtime.h>
#include <math.h>

namespace {
constexpr int kB   = 32;
constexpr int kIDF = 128;
constexpr int kCDF = 256;
constexpr int kSL  = 24;
constexpr int kQL  = 128 * 128;
constexpr int kThreads = 512;              // 512-lane contiguous window
constexpr int kQPT = 4;                    // q per thread (float4 path)
constexpr int kQPB = kThreads * kQPT;      // 2048 q per block -> 256 blocks

typedef float f32x4 __attribute__((ext_vector_type(4)));

// sourceT[b,i,l] = sum_c W[i,c] * context[b,c,l]
__global__ __launch_bounds__(256) void proj_kernel(
    const float* __restrict__ W, const float* __restrict__ ctx,
    float* __restrict__ sT_out) {
  const int b = blockIdx.x;
  __shared__ float ctxs[kCDF * kSL];
  const float* ctxb = ctx + (size_t)b * kCDF * kSL;
  for (int t = threadIdx.x; t < kCDF * kSL; t += 256) ctxs[t] = ctxb[t];
  __syncthreads();
  #pragma unroll
  for (int k = 0; k < (kIDF * kSL) / 256; ++k) {
    const int o = threadIdx.x + k * 256;
    const int i = o / kSL, l = o % kSL;
    const float* wrow = W + i * kCDF;
    float acc = 0.f;
    #pragma unroll 8
    for (int c = 0; c < kCDF; ++c) acc = fmaf(wrow[c], ctxs[c * kSL + l], acc);
    sT_out[(size_t)b * kIDF * kSL + o] = acc;
  }
}

// Main attention kernel. 512-thread blocks so each load/store burst covers
// an 8KB contiguous run of every 64KB input row (DRAM row-buffer locality
// test: r4/r5's 4KB runs delivered only ~2.6 TB/s). 1 block/CU, 8 waves/CU
// (2/SIMD) — same wave budget as r4/r5, contiguity is the only variable.
// sT reads wave-uniform -> s_load broadcast (no LDS, no barrier needed).
__global__ __launch_bounds__(kThreads) void attn_scalar(
    const float* __restrict__ input, const float* __restrict__ sT_in,
    const int* __restrict__ mask, float* __restrict__ out_wc,
    float* __restrict__ out_attn) {
  const int b  = blockIdx.y;
  const int q0 = blockIdx.x * kQPB + threadIdx.x * kQPT;
  const float* __restrict__ sTb = sT_in + (size_t)b * kIDF * kSL;

  // mask bit set == position masked with -inf (weight 0)
  unsigned mbits = 0;
  #pragma unroll
  for (int l = 0; l < kSL; ++l) mbits |= (mask[b * kSL + l] ? 1u : 0u) << l;

  f32x4 acc[kSL];
  #pragma unroll
  for (int l = 0; l < kSL; ++l) acc[l] = (f32x4)0.f;

  // attn[b,q,l] = sum_i input[b,i,q] * sT[i,l]
  const float* inb = input + (size_t)b * kIDF * kQL + q0;
  #pragma unroll 1
  for (int ii = 0; ii < kIDF; ii += 8) {
    f32x4 t[8];
    #pragma unroll
    for (int u = 0; u < 8; ++u)
      t[u] = *reinterpret_cast<const f32x4*>(inb + (size_t)(ii + u) * kQL);
    #pragma unroll
    for (int u = 0; u < 8; ++u) {
      const float* wrow = sTb + (ii + u) * kSL;  // uniform -> s_load
      #pragma unroll
      for (int l = 0; l < kSL; ++l) acc[l] += t[u] * wrow[l];
    }
  }

  // masked softmax over l (24), per q-component
  {
    float m[4] = {-INFINITY, -INFINITY, -INFINITY, -INFINITY};
    #pragma unroll
    for (int l = 0; l < kSL; ++l)
      if (!((mbits >> l) & 1u)) {
        #pragma unroll
        for (int c = 0; c < 4; ++c) m[c] = fmaxf(m[c], acc[l][c]);
      }
    float s[4] = {0.f, 0.f, 0.f, 0.f};
    #pragma unroll
    for (int l = 0; l < kSL; ++l) {
      const bool km = (mbits >> l) & 1u;
      #pragma unroll
      for (int c = 0; c < 4; ++c) {
        const float p = km ? 0.f : __expf(acc[l][c] - m[c]);
        acc[l][c] = p;
        s[c] += p;
      }
    }
    f32x4 r;
    #pragma unroll
    for (int c = 0; c < 4; ++c) r[c] = 1.f / s[c];
    #pragma unroll
    for (int l = 0; l < kSL; ++l) acc[l] *= r;
  }

  // attn_out[b,l,q] — 8KB contiguous NT store runs
  float* oa = out_attn + (size_t)b * kSL * kQL + q0;
  #pragma unroll
  for (int l = 0; l < kSL; ++l)
    __builtin_nontemporal_store(acc[l], reinterpret_cast<f32x4*>(oa + (size_t)l * kQL));

  // weightedContext[b,i,q] = sum_l sT[i,l] * attn[b,q,l]
  float* ow = out_wc + (size_t)b * kIDF * kQL + q0;
  #pragma unroll 1
  for (int ii = 0; ii < kIDF; ii += 8) {
    f32x4 res[8];
    #pragma unroll
    for (int u = 0; u < 8; ++u) res[u] = (f32x4)0.f;
    #pragma unroll
    for (int u = 0; u < 8; ++u) {
      const float* wrow = sTb + (ii + u) * kSL;  // uniform -> s_load (cached)
      #pragma unroll
      for (int l = 0; l < kSL; ++l) res[u] += acc[l] * wrow[l];
    }
    #pragma unroll
    for (int u = 0; u < 8; ++u)
      __builtin_nontemporal_store(res[u],
          reinterpret_cast<f32x4*>(ow + (size_t)(ii + u) * kQL));
  }
}

// Fallback (no workspace): compute sourceT per block in LDS.
__global__ __launch_bounds__(kThreads) void attn_fused(
    const float* __restrict__ input, const float* __restrict__ W,
    const float* __restrict__ ctx, const int* __restrict__ mask,
    float* __restrict__ out_wc, float* __restrict__ out_attn) {
  const int b  = blockIdx.y;
  const int q0 = blockIdx.x * kQPB + threadIdx.x * kQPT;
  constexpr int kSTN = kIDF * kSL;
  __shared__ float smem[kSTN + kCDF * kSL];
  float* sT = smem;
  {
    float* ctxs = smem + kSTN;
    const float* ctxb = ctx + (size_t)b * kCDF * kSL;
    for (int t = threadIdx.x; t < kCDF * kSL; t += kThreads) ctxs[t] = ctxb[t];
    __syncthreads();
    for (int k = threadIdx.x; k < kSTN; k += kThreads) {
      const int i = k / kSL, l = k % kSL;
      const float* wrow = W + i * kCDF;
      float a = 0.f;
      for (int c = 0; c < kCDF; ++c) a = fmaf(wrow[c], ctxs[c * kSL + l], a);
      sT[k] = a;
    }
  }
  __syncthreads();

  unsigned mbits = 0;
  #pragma unroll
  for (int l = 0; l < kSL; ++l) mbits |= (mask[b * kSL + l] ? 1u : 0u) << l;

  f32x4 acc[kSL];
  #pragma unroll
  for (int l = 0; l < kSL; ++l) acc[l] = (f32x4)0.f;

  const float* inb = input + (size_t)b * kIDF * kQL + q0;
  #pragma unroll 1
  for (int ii = 0; ii < kIDF; ii += 8) {
    f32x4 t[8];
    #pragma unroll
    for (int u = 0; u < 8; ++u)
      t[u] = *reinterpret_cast<const f32x4*>(inb + (size_t)(ii + u) * kQL);
    #pragma unroll
    for (int u = 0; u < 8; ++u) {
      const float* wrow = &sT[(ii + u) * kSL];
      #pragma unroll
      for (int l = 0; l < kSL; ++l) acc[l] += t[u] * wrow[l];
    }
  }

  {
    float m[4] = {-INFINITY, -INFINITY, -INFINITY, -INFINITY};
    #pragma unroll
    for (int l = 0; l < kSL; ++l)
      if (!((mbits >> l) & 1u)) {
        #pragma unroll
        for (int c = 0; c < 4; ++c) m[c] = fmaxf(m[c], acc[l][c]);
      }
    float s[4] = {0.f, 0.f, 0.f, 0.f};
    #pragma unroll
    for (int l = 0; l < kSL; ++l) {
      const bool km = (mbits >> l) & 1u;
      #pragma unroll
      for (int c = 0; c < 4; ++c) {
        const float p = km ? 0.f : __expf(acc[l][c] - m[c]);
        acc[l][c] = p;
        s[c] += p;
      }
    }
    f32x4 r;
    #pragma unroll
    for (int c = 0; c < 4; ++c) r[c] = 1.f / s[c];
    #pragma unroll
    for (int l = 0; l < kSL; ++l) acc[l] *= r;
  }

  float* oa = out_attn + (size_t)b * kSL * kQL + q0;
  #pragma unroll
  for (int l = 0; l < kSL; ++l)
    __builtin_nontemporal_store(acc[l], reinterpret_cast<f32x4*>(oa + (size_t)l * kQL));

  float* ow = out_wc + (size_t)b * kIDF * kQL + q0;
  #pragma unroll 1
  for (int ii = 0; ii < kIDF; ii += 8) {
    f32x4 res[8];
    #pragma unroll
    for (int u = 0; u < 8; ++u) res[u] = (f32x4)0.f;
    #pragma unroll
    for (int u = 0; u < 8; ++u) {
      const float* wrow = &sT[(ii + u) * kSL];
      #pragma unroll
      for (int l = 0; l < kSL; ++l) res[u] += acc[l] * wrow[l];
    }
    #pragma unroll
    for (int u = 0; u < 8; ++u)
      __builtin_nontemporal_store(res[u],
          reinterpret_cast<f32x4*>(ow + (size_t)(ii + u) * kQL));
  }
}
}  // namespace

extern "C" void kernel_launch(void* const* d_in, const int* in_sizes, int n_in,
                              void* d_out, int out_size, void* d_ws, size_t ws_size,
                              hipStream_t stream) {
  const float* input = (const float*)d_in[0];
  const float* ctx   = (const float*)d_in[1];
  const float* W     = (const float*)d_in[2];
  const int*   mask  = (const int*)d_in[3];
  float* out_wc   = (float*)d_out;
  float* out_attn = (float*)d_out + (size_t)kB * kIDF * kQL;

  const size_t st_bytes = (size_t)kB * kIDF * kSL * sizeof(float);
  dim3 grid(kQL / kQPB, kB);
  if (ws_size >= st_bytes) {
    float* sT = (float*)d_ws;
    proj_kernel<<<kB, 256, 0, stream>>>(W, ctx, sT);
    attn_scalar<<<grid, kThreads, 0, stream>>>(input, sT, mask, out_wc, out_attn);
  } else {
    attn_fused<<<grid, kThreads, 0, stream>>>(input, W, ctx, mask, out_wc, out_attn);
  }
}